// Round 1
// baseline (197.254 us; speedup 1.0000x reference)
//
#include <hip/hip_runtime.h>
#include <cstdint>

#define B_   16
#define T_   2048
#define CIN  96
#define DH   64
#define NOUT 128
#define TQ   64
#define TS   128

typedef float floatx4 __attribute__((ext_vector_type(4)));
typedef short shortx8 __attribute__((ext_vector_type(8)));

__device__ __forceinline__ unsigned short f2bf(float f) {
  unsigned int u = __float_as_uint(f);
  u += 0x7FFFu + ((u >> 16) & 1u);           // RTNE
  return (unsigned short)(u >> 16);
}
__device__ __forceinline__ floatx4 f4zero() { floatx4 v; v[0]=0.f;v[1]=0.f;v[2]=0.f;v[3]=0.f; return v; }
__device__ __forceinline__ shortx8 s8zero() { shortx8 v;
#pragma unroll
  for (int i=0;i<8;++i) v[i]=0; return v; }

// ---------------- k0: weight prep (bf16 + transpose) ----------------
// qwt  [192][96]  <- qkv_w  [96][192]
// w1t  [3][128][64]  <- conv_w1 [3][64][128]
// w2t  [3][128][128] <- conv_w2 [3][128][128] (ci<->co swap)
// dwt  [128][96] <- down_w [96][128]
__global__ __launch_bounds__(256) void k_wprep(
    const float* __restrict__ qkv_w, const float* __restrict__ cw1,
    const float* __restrict__ cw2, const float* __restrict__ dw,
    unsigned short* __restrict__ qwt, unsigned short* __restrict__ w1t,
    unsigned short* __restrict__ w2t, unsigned short* __restrict__ dwt)
{
  int o = blockIdx.x * 256 + threadIdx.x;
  if (o < 18432) {
    int co = o / 96, ci = o % 96;
    qwt[o] = f2bf(qkv_w[ci * 192 + co]);
  } else if (o < 43008) {
    int p = o - 18432;
    int tap = p / 8192, rem = p % 8192, co = rem >> 6, ci = rem & 63;
    w1t[p] = f2bf(cw1[(tap * 64 + ci) * 128 + co]);
  } else if (o < 92160) {
    int p = o - 43008;
    int tap = p / 16384, rem = p % 16384, co = rem >> 7, ci = rem & 127;
    w2t[p] = f2bf(cw2[(tap * 128 + ci) * 128 + co]);
  } else if (o < 104448) {
    int p = o - 92160;
    int co = p / 96, ci = p % 96;
    dwt[p] = f2bf(dw[ci * 128 + co]);
  }
}

// ---------------- k1: qkv projection (MFMA), writes q,k row-major + v transposed ----------------
__global__ __launch_bounds__(256) void k_qkv(
    const float* __restrict__ x, const unsigned short* __restrict__ qwt,
    const float* __restrict__ qkv_b,
    unsigned short* __restrict__ qb, unsigned short* __restrict__ kb,
    unsigned short* __restrict__ vT)
{
  __shared__ __align__(16) unsigned short Xs[64][104];   // 104*2=208B rows, 16B-aligned
  const int bx = blockIdx.x;
  const int b = bx >> 5, t0 = (bx & 31) * 64;
  const int tid = threadIdx.x, wave = tid >> 6, lane = tid & 63;
  const int l15 = lane & 15, quad = lane >> 4;

  for (int idx = tid; idx < 64 * 24; idx += 256) {
    int r = idx / 24, c = (idx % 24) * 4;
    float4 xv = *(const float4*)(x + ((size_t)(b * T_ + t0 + r)) * CIN + c);
    ushort4 o; o.x = f2bf(xv.x); o.y = f2bf(xv.y); o.z = f2bf(xv.z); o.w = f2bf(xv.w);
    *(ushort4*)(&Xs[r][c]) = o;
  }
  __syncthreads();

  floatx4 acc[4][3];
#pragma unroll
  for (int mt = 0; mt < 4; ++mt)
#pragma unroll
    for (int nt = 0; nt < 3; ++nt) acc[mt][nt] = f4zero();

#pragma unroll
  for (int ks = 0; ks < 3; ++ks) {
    shortx8 wf[3];
#pragma unroll
    for (int nt = 0; nt < 3; ++nt) {
      int j = wave * 48 + nt * 16 + l15;
      wf[nt] = *(const shortx8*)(qwt + (size_t)j * 96 + ks * 32 + quad * 8);
    }
#pragma unroll
    for (int mt = 0; mt < 4; ++mt) {
      shortx8 af = *(const shortx8*)(&Xs[mt * 16 + l15][ks * 32 + quad * 8]);
#pragma unroll
      for (int nt = 0; nt < 3; ++nt)
        acc[mt][nt] = __builtin_amdgcn_mfma_f32_16x16x32_bf16(af, wf[nt], acc[mt][nt], 0, 0, 0);
    }
  }

#pragma unroll
  for (int nt = 0; nt < 3; ++nt) {
    int j0 = wave * 48 + nt * 16;
    int j = j0 + l15;
    float bias = qkv_b[j];
#pragma unroll
    for (int mt = 0; mt < 4; ++mt) {
#pragma unroll
      for (int r = 0; r < 4; ++r) {
        int t = t0 + mt * 16 + quad * 4 + r;
        unsigned short val = f2bf(acc[mt][nt][r] + bias);
        if (j0 < 64)        qb[((size_t)b * T_ + t) * DH + j] = val;
        else if (j0 < 128)  kb[((size_t)b * T_ + t) * DH + (j - 64)] = val;
        else                vT[((size_t)b * DH + (j - 128)) * T_ + t] = val;
      }
    }
  }
}

// ---------------- k2: flash attention ----------------
__global__ __launch_bounds__(256) void k_attn(
    const unsigned short* __restrict__ qb, const unsigned short* __restrict__ kb,
    const unsigned short* __restrict__ vT, const float* __restrict__ scale_p,
    unsigned short* __restrict__ ob)
{
  __shared__ __align__(16) unsigned short Kt[TS][72];        // [s][d]
  __shared__ __align__(16) unsigned short Vt[DH][136];       // [d][s]
  __shared__ __align__(16) unsigned short Pt[4][16][136];    // per-wave [m][s]
  const int bx = blockIdx.x;
  const int b = bx >> 5, qt = bx & 31;
  const int tid = threadIdx.x, wave = tid >> 6, lane = tid & 63;
  const int l15 = lane & 15, quad = lane >> 4;
  const float scl = scale_p[0] * 1.4426950408889634f;        // softmax in exp2 domain

  const unsigned short* qrow = qb + ((size_t)b * T_ + qt * TQ + wave * 16 + l15) * DH;
  shortx8 qf0 = *(const shortx8*)(qrow + quad * 8);
  shortx8 qf1 = *(const shortx8*)(qrow + 32 + quad * 8);

  floatx4 O[4];
  float rm[4], rl[4];
#pragma unroll
  for (int i = 0; i < 4; ++i) { O[i] = f4zero(); rm[i] = -__builtin_inff(); rl[i] = 0.f; }

  const unsigned short* kbase = kb + (size_t)b * T_ * DH;
  const unsigned short* vbase = vT + (size_t)b * DH * T_;

  for (int s0 = 0; s0 < T_; s0 += TS) {
#pragma unroll
    for (int i = 0; i < 4; ++i) {            // K tile: 128 rows x 64
      int idx = tid + i * 256;
      int r = idx >> 3, c = (idx & 7) * 8;
      *(shortx8*)(&Kt[r][c]) = *(const shortx8*)(kbase + (size_t)(s0 + r) * DH + c);
    }
#pragma unroll
    for (int i = 0; i < 4; ++i) {            // V tile (already transposed): 64 rows x 128
      int idx = tid + i * 256;
      int d = idx >> 4, c = (idx & 15) * 8;
      *(shortx8*)(&Vt[d][c]) = *(const shortx8*)(vbase + (size_t)d * T_ + s0 + c);
    }
    __syncthreads();

    floatx4 S[8];
#pragma unroll
    for (int nt = 0; nt < 8; ++nt) {
      S[nt] = f4zero();
      shortx8 bk0 = *(const shortx8*)(&Kt[nt * 16 + l15][quad * 8]);
      shortx8 bk1 = *(const shortx8*)(&Kt[nt * 16 + l15][32 + quad * 8]);
      S[nt] = __builtin_amdgcn_mfma_f32_16x16x32_bf16(qf0, bk0, S[nt], 0, 0, 0);
      S[nt] = __builtin_amdgcn_mfma_f32_16x16x32_bf16(qf1, bk1, S[nt], 0, 0, 0);
    }

#pragma unroll
    for (int r = 0; r < 4; ++r) {
      float mx = -__builtin_inff();
#pragma unroll
      for (int nt = 0; nt < 8; ++nt) { S[nt][r] *= scl; mx = fmaxf(mx, S[nt][r]); }
      mx = fmaxf(mx, __shfl_xor(mx, 1));
      mx = fmaxf(mx, __shfl_xor(mx, 2));
      mx = fmaxf(mx, __shfl_xor(mx, 4));
      mx = fmaxf(mx, __shfl_xor(mx, 8));
      float mnew = fmaxf(rm[r], mx);
      float alpha = exp2f(rm[r] - mnew);
      rm[r] = mnew;
      float rs = 0.f;
#pragma unroll
      for (int nt = 0; nt < 8; ++nt) {
        float p = exp2f(S[nt][r] - mnew);
        S[nt][r] = p; rs += p;
      }
      rs += __shfl_xor(rs, 1);
      rs += __shfl_xor(rs, 2);
      rs += __shfl_xor(rs, 4);
      rs += __shfl_xor(rs, 8);
      rl[r] = rl[r] * alpha + rs;
#pragma unroll
      for (int dt = 0; dt < 4; ++dt) O[dt][r] *= alpha;
#pragma unroll
      for (int nt = 0; nt < 8; ++nt)        // P: C-layout -> LDS (A-layout readback)
        Pt[wave][quad * 4 + r][nt * 16 + l15] = f2bf(S[nt][r]);
    }
    __syncthreads();                         // P visibility (intra-wave cross-lane)

#pragma unroll
    for (int kk = 0; kk < 4; ++kk) {
      shortx8 ap = *(const shortx8*)(&Pt[wave][l15][kk * 32 + quad * 8]);
#pragma unroll
      for (int dt = 0; dt < 4; ++dt) {
        shortx8 bv = *(const shortx8*)(&Vt[dt * 16 + l15][kk * 32 + quad * 8]);
        O[dt] = __builtin_amdgcn_mfma_f32_16x16x32_bf16(ap, bv, O[dt], 0, 0, 0);
      }
    }
    __syncthreads();                         // tiles consumed before next staging
  }

#pragma unroll
  for (int r = 0; r < 4; ++r) {
    float inv = 1.f / rl[r];
    int trow = qt * TQ + wave * 16 + quad * 4 + r;
#pragma unroll
    for (int dt = 0; dt < 4; ++dt)
      ob[((size_t)b * T_ + trow) * DH + dt * 16 + l15] = f2bf(O[dt][r] * inv);
  }
}

// ---------------- k3: conv1 (K=3, same) + relu ----------------
__global__ __launch_bounds__(256) void k_conv1(
    const unsigned short* __restrict__ ab, const unsigned short* __restrict__ w1t,
    const float* __restrict__ b1, unsigned short* __restrict__ hb)
{
  __shared__ __align__(16) unsigned short At[66][72];
  const int bx = blockIdx.x;
  const int b = bx >> 5, t0 = (bx & 31) * 64;
  const int tid = threadIdx.x, wave = tid >> 6, lane = tid & 63;
  const int l15 = lane & 15, quad = lane >> 4;

  for (int idx = tid; idx < 66 * 8; idx += 256) {
    int r = idx >> 3, c = (idx & 7) * 8;
    int t = t0 + r - 1;
    shortx8 v = s8zero();
    if (t >= 0 && t < T_) v = *(const shortx8*)(ab + ((size_t)b * T_ + t) * DH + c);
    *(shortx8*)(&At[r][c]) = v;
  }
  __syncthreads();

  floatx4 acc[4][2];
#pragma unroll
  for (int mt = 0; mt < 4; ++mt) { acc[mt][0] = f4zero(); acc[mt][1] = f4zero(); }

#pragma unroll
  for (int tap = 0; tap < 3; ++tap) {
#pragma unroll
    for (int ks = 0; ks < 2; ++ks) {
      shortx8 wf[2];
#pragma unroll
      for (int ct = 0; ct < 2; ++ct) {
        int co = wave * 32 + ct * 16 + l15;
        wf[ct] = *(const shortx8*)(w1t + ((size_t)tap * 128 + co) * 64 + ks * 32 + quad * 8);
      }
#pragma unroll
      for (int mt = 0; mt < 4; ++mt) {
        shortx8 af = *(const shortx8*)(&At[mt * 16 + l15 + tap][ks * 32 + quad * 8]);
        acc[mt][0] = __builtin_amdgcn_mfma_f32_16x16x32_bf16(af, wf[0], acc[mt][0], 0, 0, 0);
        acc[mt][1] = __builtin_amdgcn_mfma_f32_16x16x32_bf16(af, wf[1], acc[mt][1], 0, 0, 0);
      }
    }
  }

#pragma unroll
  for (int ct = 0; ct < 2; ++ct) {
    int co = wave * 32 + ct * 16 + l15;
    float bias = b1[co];
#pragma unroll
    for (int mt = 0; mt < 4; ++mt)
#pragma unroll
      for (int r = 0; r < 4; ++r) {
        int t = t0 + mt * 16 + quad * 4 + r;
        hb[((size_t)b * T_ + t) * NOUT + co] = f2bf(fmaxf(acc[mt][ct][r] + bias, 0.f));
      }
  }
}

// ---------------- k4: conv2 + relu + residual (x@down_w)*(2049/2048) + relu ----------------
__global__ __launch_bounds__(256) void k_conv2(
    const unsigned short* __restrict__ hb, const float* __restrict__ x,
    const unsigned short* __restrict__ w2t, const unsigned short* __restrict__ dwt,
    const float* __restrict__ b2, float* __restrict__ out)
{
  __shared__ __align__(16) unsigned short Ht[66][136];
  __shared__ __align__(16) unsigned short Xt[64][104];
  const int bx = blockIdx.x;
  const int b = bx >> 5, t0 = (bx & 31) * 64;
  const int tid = threadIdx.x, wave = tid >> 6, lane = tid & 63;
  const int l15 = lane & 15, quad = lane >> 4;

  for (int idx = tid; idx < 66 * 16; idx += 256) {
    int r = idx >> 4, c = (idx & 15) * 8;
    int t = t0 + r - 1;
    shortx8 v = s8zero();
    if (t >= 0 && t < T_) v = *(const shortx8*)(hb + ((size_t)b * T_ + t) * NOUT + c);
    *(shortx8*)(&Ht[r][c]) = v;
  }
  for (int idx = tid; idx < 64 * 24; idx += 256) {
    int r = idx / 24, c = (idx % 24) * 4;
    float4 xv = *(const float4*)(x + ((size_t)(b * T_ + t0 + r)) * CIN + c);
    ushort4 o; o.x = f2bf(xv.x); o.y = f2bf(xv.y); o.z = f2bf(xv.z); o.w = f2bf(xv.w);
    *(ushort4*)(&Xt[r][c]) = o;
  }
  __syncthreads();

  floatx4 a2[4][2], ar[4][2];
#pragma unroll
  for (int mt = 0; mt < 4; ++mt) { a2[mt][0]=f4zero(); a2[mt][1]=f4zero(); ar[mt][0]=f4zero(); ar[mt][1]=f4zero(); }

#pragma unroll
  for (int tap = 0; tap < 3; ++tap) {
#pragma unroll
    for (int ks = 0; ks < 4; ++ks) {
      shortx8 wf[2];
#pragma unroll
      for (int ct = 0; ct < 2; ++ct) {
        int co = wave * 32 + ct * 16 + l15;
        wf[ct] = *(const shortx8*)(w2t + ((size_t)tap * 128 + co) * 128 + ks * 32 + quad * 8);
      }
#pragma unroll
      for (int mt = 0; mt < 4; ++mt) {
        shortx8 af = *(const shortx8*)(&Ht[mt * 16 + l15 + tap][ks * 32 + quad * 8]);
        a2[mt][0] = __builtin_amdgcn_mfma_f32_16x16x32_bf16(af, wf[0], a2[mt][0], 0, 0, 0);
        a2[mt][1] = __builtin_amdgcn_mfma_f32_16x16x32_bf16(af, wf[1], a2[mt][1], 0, 0, 0);
      }
    }
  }
#pragma unroll
  for (int ks = 0; ks < 3; ++ks) {
    shortx8 wf[2];
#pragma unroll
    for (int ct = 0; ct < 2; ++ct) {
      int co = wave * 32 + ct * 16 + l15;
      wf[ct] = *(const shortx8*)(dwt + (size_t)co * 96 + ks * 32 + quad * 8);
    }
#pragma unroll
    for (int mt = 0; mt < 4; ++mt) {
      shortx8 af = *(const shortx8*)(&Xt[mt * 16 + l15][ks * 32 + quad * 8]);
      ar[mt][0] = __builtin_amdgcn_mfma_f32_16x16x32_bf16(af, wf[0], ar[mt][0], 0, 0, 0);
      ar[mt][1] = __builtin_amdgcn_mfma_f32_16x16x32_bf16(af, wf[1], ar[mt][1], 0, 0, 0);
    }
  }

  const float kres = 1.0f + 1.0f / 2048.0f;   // res + en_res (weight_x == 1/T exactly)
#pragma unroll
  for (int ct = 0; ct < 2; ++ct) {
    int co = wave * 32 + ct * 16 + l15;
    float bias = b2[co];
#pragma unroll
    for (int mt = 0; mt < 4; ++mt)
#pragma unroll
      for (int r = 0; r < 4; ++r) {
        int t = t0 + mt * 16 + quad * 4 + r;
        float o2 = fmaxf(a2[mt][ct][r] + bias, 0.f);
        out[((size_t)b * T_ + t) * NOUT + co] = fmaxf(o2 + ar[mt][ct][r] * kres, 0.f);
      }
  }
}

// ---------------- launch ----------------
extern "C" void kernel_launch(void* const* d_in, const int* in_sizes, int n_in,
                              void* d_out, int out_size, void* d_ws, size_t ws_size,
                              hipStream_t stream) {
  const float* x      = (const float*)d_in[0];
  const float* qkv_w  = (const float*)d_in[1];
  const float* qkv_b  = (const float*)d_in[2];
  const float* scale  = (const float*)d_in[3];
  const float* cw1    = (const float*)d_in[4];
  const float* cb1    = (const float*)d_in[5];
  const float* cw2    = (const float*)d_in[6];
  const float* cb2    = (const float*)d_in[7];
  const float* dw     = (const float*)d_in[8];

  char* ws = (char*)d_ws;
  unsigned short* qb  = (unsigned short*)(ws + 0);          // [B,T,64]
  unsigned short* kb  = (unsigned short*)(ws + 4194304);    // [B,T,64]
  unsigned short* vT  = (unsigned short*)(ws + 8388608);    // [B,64,T]
  unsigned short* ab  = (unsigned short*)(ws + 12582912);   // [B,T,64]
  unsigned short* hb  = (unsigned short*)(ws + 16777216);   // [B,T,128]
  unsigned short* qwt = (unsigned short*)(ws + 25165824);   // [192][96]
  unsigned short* w1t = (unsigned short*)(ws + 25202688);   // [3][128][64]
  unsigned short* w2t = (unsigned short*)(ws + 25251840);   // [3][128][128]
  unsigned short* dwt = (unsigned short*)(ws + 25350144);   // [128][96]

  k_wprep<<<408, 256, 0, stream>>>(qkv_w, cw1, cw2, dw, qwt, w1t, w2t, dwt);
  k_qkv  <<<512, 256, 0, stream>>>(x, qwt, qkv_b, qb, kb, vT);
  k_attn <<<512, 256, 0, stream>>>(qb, kb, vT, scale, ab);
  k_conv1<<<512, 256, 0, stream>>>(ab, w1t, cb1, hb);
  k_conv2<<<512, 256, 0, stream>>>(hb, x, w2t, dwt, cb2, (float*)d_out);
}

// Round 2
// 155.029 us; speedup vs baseline: 1.2724x; 1.2724x over previous
//
#include <hip/hip_runtime.h>
#include <cstdint>

#define B_   16
#define T_   2048
#define CIN  96
#define DH   64
#define NOUT 128

typedef float floatx4 __attribute__((ext_vector_type(4)));
typedef short shortx8 __attribute__((ext_vector_type(8)));

__device__ __forceinline__ unsigned short f2bf(float f) {
  unsigned int u = __float_as_uint(f);
  u += 0x7FFFu + ((u >> 16) & 1u);           // RTNE
  return (unsigned short)(u >> 16);
}
__device__ __forceinline__ floatx4 f4zero() { floatx4 v; v[0]=0.f;v[1]=0.f;v[2]=0.f;v[3]=0.f; return v; }
__device__ __forceinline__ shortx8 s8zero() { shortx8 v;
#pragma unroll
  for (int i=0;i<8;++i) v[i]=0; return v; }

// ---------------- k0: weight prep (bf16 + transpose) ----------------
__global__ __launch_bounds__(256) void k_wprep(
    const float* __restrict__ qkv_w, const float* __restrict__ cw1,
    const float* __restrict__ cw2, const float* __restrict__ dw,
    unsigned short* __restrict__ qwt, unsigned short* __restrict__ w1t,
    unsigned short* __restrict__ w2t, unsigned short* __restrict__ dwt)
{
  int o = blockIdx.x * 256 + threadIdx.x;
  if (o < 18432) {
    int co = o / 96, ci = o % 96;
    qwt[o] = f2bf(qkv_w[ci * 192 + co]);
  } else if (o < 43008) {
    int p = o - 18432;
    int tap = p / 8192, rem = p % 8192, co = rem >> 6, ci = rem & 63;
    w1t[p] = f2bf(cw1[(tap * 64 + ci) * 128 + co]);
  } else if (o < 92160) {
    int p = o - 43008;
    int tap = p / 16384, rem = p % 16384, co = rem >> 7, ci = rem & 127;
    w2t[p] = f2bf(cw2[(tap * 128 + ci) * 128 + co]);
  } else if (o < 104448) {
    int p = o - 92160;
    int co = p / 96, ci = p % 96;
    dwt[p] = f2bf(dw[ci * 128 + co]);
  }
}

// ---------------- k1: qkv projection; q pre-scaled by scale*log2(e) ----------------
__global__ __launch_bounds__(256) void k_qkv(
    const float* __restrict__ x, const unsigned short* __restrict__ qwt,
    const float* __restrict__ qkv_b, const float* __restrict__ scale_p,
    unsigned short* __restrict__ qb, unsigned short* __restrict__ kb,
    unsigned short* __restrict__ vT)
{
  __shared__ __align__(16) unsigned short Xs[64][104];
  const int bx = blockIdx.x;
  const int b = bx >> 5, t0 = (bx & 31) * 64;
  const int tid = threadIdx.x, wave = tid >> 6, lane = tid & 63;
  const int l15 = lane & 15, quad = lane >> 4;
  const float scl2 = scale_p[0] * 1.4426950408889634f;

  for (int idx = tid; idx < 64 * 24; idx += 256) {
    int r = idx / 24, c = (idx % 24) * 4;
    float4 xv = *(const float4*)(x + ((size_t)(b * T_ + t0 + r)) * CIN + c);
    ushort4 o; o.x = f2bf(xv.x); o.y = f2bf(xv.y); o.z = f2bf(xv.z); o.w = f2bf(xv.w);
    *(ushort4*)(&Xs[r][c]) = o;
  }
  __syncthreads();

  floatx4 acc[4][3];
#pragma unroll
  for (int mt = 0; mt < 4; ++mt)
#pragma unroll
    for (int nt = 0; nt < 3; ++nt) acc[mt][nt] = f4zero();

#pragma unroll
  for (int ks = 0; ks < 3; ++ks) {
    shortx8 wf[3];
#pragma unroll
    for (int nt = 0; nt < 3; ++nt) {
      int j = wave * 48 + nt * 16 + l15;
      wf[nt] = *(const shortx8*)(qwt + (size_t)j * 96 + ks * 32 + quad * 8);
    }
#pragma unroll
    for (int mt = 0; mt < 4; ++mt) {
      shortx8 af = *(const shortx8*)(&Xs[mt * 16 + l15][ks * 32 + quad * 8]);
#pragma unroll
      for (int nt = 0; nt < 3; ++nt)
        acc[mt][nt] = __builtin_amdgcn_mfma_f32_16x16x32_bf16(af, wf[nt], acc[mt][nt], 0, 0, 0);
    }
  }

#pragma unroll
  for (int nt = 0; nt < 3; ++nt) {
    int j0 = wave * 48 + nt * 16;
    int j = j0 + l15;
    float bias = qkv_b[j];
#pragma unroll
    for (int mt = 0; mt < 4; ++mt) {
#pragma unroll
      for (int r = 0; r < 4; ++r) {
        int t = t0 + mt * 16 + quad * 4 + r;
        float v = acc[mt][nt][r] + bias;
        if (j0 < 64)        qb[((size_t)b * T_ + t) * DH + j] = f2bf(v * scl2);
        else if (j0 < 128)  kb[((size_t)b * T_ + t) * DH + (j - 64)] = f2bf(v);
        else                vT[((size_t)b * DH + (j - 128)) * T_ + t] = f2bf(v);
      }
    }
  }
}

// ---------------- k2: streaming attention, no-max softmax, split-S 2-way ----------------
// Writes UNNORMALIZED O partials (fp32) into opart[half][b][t][d] and row-sums l
// (from a ones-column in V via MFMA) into lws[half][b][t].
__global__ __launch_bounds__(256) void k_attn(
    const unsigned short* __restrict__ qb, const unsigned short* __restrict__ kb,
    const unsigned short* __restrict__ vT,
    float* __restrict__ opart, float* __restrict__ lws)
{
  __shared__ __align__(16) unsigned short Kt[64][72];    // [s][d]
  __shared__ __align__(16) unsigned short Vt[80][72];    // [d][s]; rows 64..79: ones/zeros
  __shared__ __align__(16) unsigned short Pt[4][16][72]; // per-wave [m][s], col-swizzled
  const int bx = blockIdx.x;
  const int half = bx & 1, qt = (bx >> 1) & 31, b = bx >> 6;
  const int tid = threadIdx.x, wave = tid >> 6, lane = tid & 63;
  const int l15 = lane & 15, quad = lane >> 4;

  const unsigned short* qrow = qb + ((size_t)b * T_ + qt * 64 + wave * 16 + l15) * DH;
  shortx8 qf0 = *(const shortx8*)(qrow + quad * 8);
  shortx8 qf1 = *(const shortx8*)(qrow + 32 + quad * 8);

  floatx4 O[5];
#pragma unroll
  for (int i = 0; i < 5; ++i) O[i] = f4zero();

  const unsigned short* kbase = kb + (size_t)b * T_ * DH + (size_t)half * 1024 * DH;
  const unsigned short* vbase = vT + (size_t)b * DH * T_ + half * 1024;

  // ones-column rows of Vt (d=64 -> 1.0, d=65..79 -> 0), written once
  for (int idx = tid; idx < 16 * 72; idx += 256) {
    int r = idx / 72, c = idx % 72;
    Vt[64 + r][c] = (r == 0) ? (unsigned short)0x3F80 : (unsigned short)0;
  }

  const int kr0 = tid >> 3, kc = (tid & 7) * 8;          // staging coords
  shortx8 pk[2], pv[2];
#pragma unroll
  for (int i = 0; i < 2; ++i) {                          // prefetch tile 0
    pk[i] = *(const shortx8*)(kbase + (size_t)(kr0 + i * 32) * DH + kc);
    pv[i] = *(const shortx8*)(vbase + (size_t)(kr0 + i * 32) * T_ + kc);
  }

  for (int t = 0; t < 16; ++t) {
#pragma unroll
    for (int i = 0; i < 2; ++i) {                        // regs -> LDS
      *(shortx8*)(&Kt[kr0 + i * 32][kc]) = pk[i];
      *(shortx8*)(&Vt[kr0 + i * 32][kc]) = pv[i];
    }
    __syncthreads();                                     // tiles (and ones rows) visible

    if (t < 15) {                                        // prefetch next tile
      int s0 = (t + 1) * 64;
#pragma unroll
      for (int i = 0; i < 2; ++i) {
        pk[i] = *(const shortx8*)(kbase + (size_t)(s0 + kr0 + i * 32) * DH + kc);
        pv[i] = *(const shortx8*)(vbase + (size_t)(kr0 + i * 32) * T_ + s0 + kc);
      }
    }

    floatx4 S[4];
#pragma unroll
    for (int nt = 0; nt < 4; ++nt) {                     // S = q.K^T (q pre-scaled)
      S[nt] = f4zero();
      shortx8 bk0 = *(const shortx8*)(&Kt[nt * 16 + l15][quad * 8]);
      shortx8 bk1 = *(const shortx8*)(&Kt[nt * 16 + l15][32 + quad * 8]);
      S[nt] = __builtin_amdgcn_mfma_f32_16x16x32_bf16(qf0, bk0, S[nt], 0, 0, 0);
      S[nt] = __builtin_amdgcn_mfma_f32_16x16x32_bf16(qf1, bk1, S[nt], 0, 0, 0);
    }

    // P = exp2(S); write to per-wave LDS with col rotation 16*quad (bank-disjoint)
#pragma unroll
    for (int r = 0; r < 4; ++r)
#pragma unroll
      for (int nt = 0; nt < 4; ++nt) {
        float p = exp2f(S[nt][r]);
        Pt[wave][quad * 4 + r][(nt * 16 + l15 + (quad << 4)) & 63] = f2bf(p);
      }

    // O += P.V (intra-wave LDS round-trip; compiler orders via lgkmcnt, no barrier)
#pragma unroll
    for (int kk = 0; kk < 2; ++kk) {
      int pcol = (kk * 32 + quad * 8 + ((l15 >> 2) << 4)) & 63;
      shortx8 ap = *(const shortx8*)(&Pt[wave][l15][pcol]);
#pragma unroll
      for (int dt = 0; dt < 5; ++dt) {
        shortx8 bv = *(const shortx8*)(&Vt[dt * 16 + l15][kk * 32 + quad * 8]);
        O[dt] = __builtin_amdgcn_mfma_f32_16x16x32_bf16(ap, bv, O[dt], 0, 0, 0);
      }
    }
    __syncthreads();                                     // K/V consumed before restage
  }

  float* obase = opart + (((size_t)(half * B_ + b) * T_) + qt * 64 + wave * 16) * DH;
#pragma unroll
  for (int r = 0; r < 4; ++r) {
    int row = quad * 4 + r;
#pragma unroll
    for (int dt = 0; dt < 4; ++dt)
      obase[(size_t)row * DH + dt * 16 + l15] = O[dt][r];
    if (l15 == 0)
      lws[half * (B_ * T_) + b * T_ + qt * 64 + wave * 16 + row] = O[4][r];
  }
}

// ---------------- k2b: combine split-S partials -> ab (bf16) ----------------
__global__ __launch_bounds__(256) void k_comb(
    const float* __restrict__ opart, const float* __restrict__ lws,
    unsigned short* __restrict__ ab)
{
  int g = blockIdx.x * 256 + threadIdx.x;      // [B*T][16] groups of 4 d
  int bt = g >> 4, dg = (g & 15) * 4;
  const size_t HS = (size_t)B_ * T_ * DH;      // half stride
  float4 p0 = *(const float4*)(opart + (size_t)bt * DH + dg);
  float4 p1 = *(const float4*)(opart + HS + (size_t)bt * DH + dg);
  float inv = 1.f / (lws[bt] + lws[B_ * T_ + bt]);
  ushort4 o;
  o.x = f2bf((p0.x + p1.x) * inv);
  o.y = f2bf((p0.y + p1.y) * inv);
  o.z = f2bf((p0.z + p1.z) * inv);
  o.w = f2bf((p0.w + p1.w) * inv);
  *(ushort4*)(ab + (size_t)bt * DH + dg) = o;
}

// ---------------- k3: conv1 (K=3, same) + relu ----------------
__global__ __launch_bounds__(256) void k_conv1(
    const unsigned short* __restrict__ ab, const unsigned short* __restrict__ w1t,
    const float* __restrict__ b1, unsigned short* __restrict__ hb)
{
  __shared__ __align__(16) unsigned short At[66][72];
  const int bx = blockIdx.x;
  const int b = bx >> 5, t0 = (bx & 31) * 64;
  const int tid = threadIdx.x, wave = tid >> 6, lane = tid & 63;
  const int l15 = lane & 15, quad = lane >> 4;

  for (int idx = tid; idx < 66 * 8; idx += 256) {
    int r = idx >> 3, c = (idx & 7) * 8;
    int t = t0 + r - 1;
    shortx8 v = s8zero();
    if (t >= 0 && t < T_) v = *(const shortx8*)(ab + ((size_t)b * T_ + t) * DH + c);
    *(shortx8*)(&At[r][c]) = v;
  }
  __syncthreads();

  floatx4 acc[4][2];
#pragma unroll
  for (int mt = 0; mt < 4; ++mt) { acc[mt][0] = f4zero(); acc[mt][1] = f4zero(); }

#pragma unroll
  for (int tap = 0; tap < 3; ++tap) {
#pragma unroll
    for (int ks = 0; ks < 2; ++ks) {
      shortx8 wf[2];
#pragma unroll
      for (int ct = 0; ct < 2; ++ct) {
        int co = wave * 32 + ct * 16 + l15;
        wf[ct] = *(const shortx8*)(w1t + ((size_t)tap * 128 + co) * 64 + ks * 32 + quad * 8);
      }
#pragma unroll
      for (int mt = 0; mt < 4; ++mt) {
        shortx8 af = *(const shortx8*)(&At[mt * 16 + l15 + tap][ks * 32 + quad * 8]);
        acc[mt][0] = __builtin_amdgcn_mfma_f32_16x16x32_bf16(af, wf[0], acc[mt][0], 0, 0, 0);
        acc[mt][1] = __builtin_amdgcn_mfma_f32_16x16x32_bf16(af, wf[1], acc[mt][1], 0, 0, 0);
      }
    }
  }

#pragma unroll
  for (int ct = 0; ct < 2; ++ct) {
    int co = wave * 32 + ct * 16 + l15;
    float bias = b1[co];
#pragma unroll
    for (int mt = 0; mt < 4; ++mt)
#pragma unroll
      for (int r = 0; r < 4; ++r) {
        int t = t0 + mt * 16 + quad * 4 + r;
        hb[((size_t)b * T_ + t) * NOUT + co] = f2bf(fmaxf(acc[mt][ct][r] + bias, 0.f));
      }
  }
}

// ---------------- k4: conv2 + relu + residual + relu ----------------
__global__ __launch_bounds__(256) void k_conv2(
    const unsigned short* __restrict__ hb, const float* __restrict__ x,
    const unsigned short* __restrict__ w2t, const unsigned short* __restrict__ dwt,
    const float* __restrict__ b2, float* __restrict__ out)
{
  __shared__ __align__(16) unsigned short Ht[66][136];
  __shared__ __align__(16) unsigned short Xt[64][104];
  const int bx = blockIdx.x;
  const int b = bx >> 5, t0 = (bx & 31) * 64;
  const int tid = threadIdx.x, wave = tid >> 6, lane = tid & 63;
  const int l15 = lane & 15, quad = lane >> 4;

  for (int idx = tid; idx < 66 * 16; idx += 256) {
    int r = idx >> 4, c = (idx & 15) * 8;
    int t = t0 + r - 1;
    shortx8 v = s8zero();
    if (t >= 0 && t < T_) v = *(const shortx8*)(hb + ((size_t)b * T_ + t) * NOUT + c);
    *(shortx8*)(&Ht[r][c]) = v;
  }
  for (int idx = tid; idx < 64 * 24; idx += 256) {
    int r = idx / 24, c = (idx % 24) * 4;
    float4 xv = *(const float4*)(x + ((size_t)(b * T_ + t0 + r)) * CIN + c);
    ushort4 o; o.x = f2bf(xv.x); o.y = f2bf(xv.y); o.z = f2bf(xv.z); o.w = f2bf(xv.w);
    *(ushort4*)(&Xt[r][c]) = o;
  }
  __syncthreads();

  floatx4 a2[4][2], ar[4][2];
#pragma unroll
  for (int mt = 0; mt < 4; ++mt) { a2[mt][0]=f4zero(); a2[mt][1]=f4zero(); ar[mt][0]=f4zero(); ar[mt][1]=f4zero(); }

#pragma unroll
  for (int tap = 0; tap < 3; ++tap) {
#pragma unroll
    for (int ks = 0; ks < 4; ++ks) {
      shortx8 wf[2];
#pragma unroll
      for (int ct = 0; ct < 2; ++ct) {
        int co = wave * 32 + ct * 16 + l15;
        wf[ct] = *(const shortx8*)(w2t + ((size_t)tap * 128 + co) * 128 + ks * 32 + quad * 8);
      }
#pragma unroll
      for (int mt = 0; mt < 4; ++mt) {
        shortx8 af = *(const shortx8*)(&Ht[mt * 16 + l15 + tap][ks * 32 + quad * 8]);
        a2[mt][0] = __builtin_amdgcn_mfma_f32_16x16x32_bf16(af, wf[0], a2[mt][0], 0, 0, 0);
        a2[mt][1] = __builtin_amdgcn_mfma_f32_16x16x32_bf16(af, wf[1], a2[mt][1], 0, 0, 0);
      }
    }
  }
#pragma unroll
  for (int ks = 0; ks < 3; ++ks) {
    shortx8 wf[2];
#pragma unroll
    for (int ct = 0; ct < 2; ++ct) {
      int co = wave * 32 + ct * 16 + l15;
      wf[ct] = *(const shortx8*)(dwt + (size_t)co * 96 + ks * 32 + quad * 8);
    }
#pragma unroll
    for (int mt = 0; mt < 4; ++mt) {
      shortx8 af = *(const shortx8*)(&Xt[mt * 16 + l15][ks * 32 + quad * 8]);
      ar[mt][0] = __builtin_amdgcn_mfma_f32_16x16x32_bf16(af, wf[0], ar[mt][0], 0, 0, 0);
      ar[mt][1] = __builtin_amdgcn_mfma_f32_16x16x32_bf16(af, wf[1], ar[mt][1], 0, 0, 0);
    }
  }

  const float kres = 1.0f + 1.0f / 2048.0f;
#pragma unroll
  for (int ct = 0; ct < 2; ++ct) {
    int co = wave * 32 + ct * 16 + l15;
    float bias = b2[co];
#pragma unroll
    for (int mt = 0; mt < 4; ++mt)
#pragma unroll
      for (int r = 0; r < 4; ++r) {
        int t = t0 + mt * 16 + quad * 4 + r;
        float o2 = fmaxf(a2[mt][ct][r] + bias, 0.f);
        out[((size_t)b * T_ + t) * NOUT + co] = fmaxf(o2 + ar[mt][ct][r] * kres, 0.f);
      }
  }
}

// ---------------- launch ----------------
extern "C" void kernel_launch(void* const* d_in, const int* in_sizes, int n_in,
                              void* d_out, int out_size, void* d_ws, size_t ws_size,
                              hipStream_t stream) {
  const float* x      = (const float*)d_in[0];
  const float* qkv_w  = (const float*)d_in[1];
  const float* qkv_b  = (const float*)d_in[2];
  const float* scale  = (const float*)d_in[3];
  const float* cw1    = (const float*)d_in[4];
  const float* cb1    = (const float*)d_in[5];
  const float* cw2    = (const float*)d_in[6];
  const float* cb2    = (const float*)d_in[7];
  const float* dw     = (const float*)d_in[8];

  char* ws = (char*)d_ws;
  unsigned short* qb  = (unsigned short*)(ws + 0);          // [B,T,64]
  unsigned short* kb  = (unsigned short*)(ws + 4194304);    // [B,T,64]
  unsigned short* vT  = (unsigned short*)(ws + 8388608);    // [B,64,T]
  unsigned short* ab  = (unsigned short*)(ws + 12582912);   // [B,T,64]
  unsigned short* hb  = (unsigned short*)(ws + 16777216);   // [B,T,128]
  unsigned short* qwt = (unsigned short*)(ws + 25165824);   // [192][96]
  unsigned short* w1t = (unsigned short*)(ws + 25202688);   // [3][128][64]
  unsigned short* w2t = (unsigned short*)(ws + 25251840);   // [3][128][128]
  unsigned short* dwt = (unsigned short*)(ws + 25350144);   // [128][96]
  float*          lws = (float*)(ws + 25374720);            // [2][B,T] row-sums

  float* opart = (float*)d_out;  // [2][B,T,64] fp32 partials; overwritten by k_conv2

  k_wprep<<<408, 256, 0, stream>>>(qkv_w, cw1, cw2, dw, qwt, w1t, w2t, dwt);
  k_qkv  <<<512, 256, 0, stream>>>(x, qwt, qkv_b, scale, qb, kb, vT);
  k_attn <<<1024, 256, 0, stream>>>(qb, kb, vT, opart, lws);
  k_comb <<<2048, 256, 0, stream>>>(opart, lws, ab);
  k_conv1<<<512, 256, 0, stream>>>(ab, w1t, cb1, hb);
  k_conv2<<<512, 256, 0, stream>>>(hb, x, w2t, dwt, cb2, (float*)d_out);
}